// Round 1
// 385.423 us; speedup vs baseline: 1.0137x; 1.0137x over previous
//
#include <hip/hip_runtime.h>
#include <stdint.h>

#define BTOK 16384
#define DM   512
#define DFF  2048
#define NE   8
#define NPAIR (BTOK*2)
#define MAXTA 24          // max 256-row tiles per expert (balanced routing: ~16)
#define MAXTB 48          // max 128-row tiles per expert

typedef short s16x8 __attribute__((ext_vector_type(8)));   // 8 bf16 in 4 VGPRs
typedef float f32x4 __attribute__((ext_vector_type(4)));

// fp32 -> bf16 RNE (inputs finite)
__device__ __forceinline__ uint16_t f2b(float f) {
  uint32_t u = __float_as_uint(f);
  u += 0x7fff + ((u >> 16) & 1);
  return (uint16_t)(u >> 16);
}

// async global->LDS, 16B per lane; lds ptr must be wave-uniform base (HW adds lane*16)
__device__ __forceinline__ void g2l16(const void* gp, void* lp) {
  __builtin_amdgcn_global_load_lds(
      (__attribute__((address_space(1))) void*)(void*)gp,
      (__attribute__((address_space(3))) void*)lp, 16, 0, 0);
}

// ---------- merged transpose+convert: z<8 -> W1 [D][DFF]->[DFF][D], z>=8 -> W2 [DFF][D]->[D][DFF] ----------
__global__ void k_tr(const float* __restrict__ w1, const float* __restrict__ w2,
                     uint16_t* __restrict__ w1t, uint16_t* __restrict__ w2t) {
  __shared__ float t[32][33];
  int z = blockIdx.z, bx = blockIdx.x;
  int R, C, c0, r0;
  const float* src;
  uint16_t* dst;
  if (z < 8) { R = DM; C = DFF; c0 = (bx & 63) * 32; r0 = (bx >> 6) * 32;
               src = w1 + (size_t)z * R * C; dst = w1t + (size_t)z * R * C; }
  else       { R = DFF; C = DM; c0 = (bx & 15) * 32; r0 = (bx >> 4) * 32;
               src = w2 + (size_t)(z - 8) * R * C; dst = w2t + (size_t)(z - 8) * R * C; }
  int tx = threadIdx.x, ty = threadIdx.y;
#pragma unroll
  for (int j = 0; j < 4; j++)
    t[ty + j * 8][tx] = src[(size_t)(r0 + ty + j * 8) * C + c0 + tx];
  __syncthreads();
#pragma unroll
  for (int j = 0; j < 4; j++)
    dst[(size_t)(c0 + ty + j * 8) * R + r0 + tx] = f2b(t[tx][ty + j * 8]);
}

// ---- gate + x->bf16: wave-per-token x16, wg in registers, LDS histogram; then convert block's x slab ----
__global__ __launch_bounds__(256) void k_route(const float* __restrict__ x,
                                               const float* __restrict__ wg,
                                               int* __restrict__ counts,
                                               int* __restrict__ tk_e, float* __restrict__ tk_w,
                                               uint16_t* __restrict__ xb) {
  __shared__ int hist[NE];
  int tid = threadIdx.x, lane = tid & 63, wave = tid >> 6;
  if (tid < NE) hist[tid] = 0;
  __syncthreads();

  float wv[8][8];
#pragma unroll
  for (int j = 0; j < 8; j++) {
    const float4* wr = (const float4*)(wg + (size_t)(j * 64 + lane) * NE);
    float4 a = wr[0], b = wr[1];
    wv[j][0] = a.x; wv[j][1] = a.y; wv[j][2] = a.z; wv[j][3] = a.w;
    wv[j][4] = b.x; wv[j][5] = b.y; wv[j][6] = b.z; wv[j][7] = b.w;
  }

  int tok0 = blockIdx.x * 64 + wave * 16;
  for (int tt = 0; tt < 16; tt++) {
    int tok = tok0 + tt;
    const float* xr = x + (size_t)tok * DM;
    float xv[8];
#pragma unroll
    for (int j = 0; j < 8; j++) xv[j] = xr[j * 64 + lane];
    float acc[NE];
#pragma unroll
    for (int e = 0; e < NE; e++) acc[e] = 0.f;
#pragma unroll
    for (int j = 0; j < 8; j++)
#pragma unroll
      for (int e = 0; e < NE; e++) acc[e] += xv[j] * wv[j][e];
#pragma unroll
    for (int e = 0; e < NE; e++) {
#pragma unroll
      for (int off = 32; off > 0; off >>= 1) acc[e] += __shfl_xor(acc[e], off, 64);
    }
    if (lane == 0) {
      float mx = acc[0];
      for (int e = 1; e < NE; e++) mx = fmaxf(mx, acc[e]);
      float p[NE], s = 0.f;
      for (int e = 0; e < NE; e++) { p[e] = __expf(acc[e] - mx); s += p[e]; }
      float inv = 1.f / s;
      int e0 = 0; float v0 = p[0];
      for (int e = 1; e < NE; e++) if (p[e] > v0) { v0 = p[e]; e0 = e; }  // strict > = top_k tiebreak
      int e1 = -1; float v1 = -1.f;
      for (int e = 0; e < NE; e++) if (e != e0 && p[e] > v1) { v1 = p[e]; e1 = e; }
      tk_e[tok * 2]     = e0; tk_w[tok * 2]     = v0 * inv;
      tk_e[tok * 2 + 1] = e1; tk_w[tok * 2 + 1] = v1 * inv;
      atomicAdd(&hist[e0], 1);
      atomicAdd(&hist[e1], 1);
    }
  }
  // convert this block's 64-token slab (L2-hot) to bf16
  const float* xs = x + (size_t)blockIdx.x * 32768;
  uint16_t* xd = xb + (size_t)blockIdx.x * 32768;
#pragma unroll
  for (int i = 0; i < 16; i++) {
    int o = i * 2048 + tid * 8;
    float4 a = *(const float4*)(xs + o);
    float4 b = *(const float4*)(xs + o + 4);
    uint16_t v[8] = {f2b(a.x), f2b(a.y), f2b(a.z), f2b(a.w),
                     f2b(b.x), f2b(b.y), f2b(b.z), f2b(b.w)};
    *(s16x8*)(xd + o) = *(s16x8*)v;
  }
  __syncthreads();
  if (tid < NE) atomicAdd(&counts[tid], hist[tid]);
}

// ---------------- prefix sums + tile maps at 256 (gemm1) and 128 (gemm2) granularity ----------------
__global__ void k_setup(const int* __restrict__ counts, int* __restrict__ offsets,
                        int* __restrict__ trA, int* __restrict__ tcntA, int* __restrict__ tstartA,
                        int* __restrict__ trB, int* __restrict__ tcntB, int* __restrict__ tstartB) {
  if (threadIdx.x != 0 || blockIdx.x != 0) return;
  int off = 0;
  for (int e = 0; e < NE; e++) { offsets[e] = off; off += counts[e]; }
  offsets[NE] = off;
  int nt = 0;
  for (int e = 0; e < NE; e++) {
    tstartA[e] = nt; int c = 0;
    for (int r = offsets[e]; r < offsets[e + 1]; r += 256) { trA[nt++] = r; c++; }
    tcntA[e] = c;
  }
  int nb = 0;
  for (int e = 0; e < NE; e++) {
    tstartB[e] = nb; int c = 0;
    for (int r = offsets[e]; r < offsets[e + 1]; r += 128) { trB[nb++] = r; c++; }
    tcntB[e] = c;
  }
}

// ------- build compact slot lists + inverse map -------
__global__ __launch_bounds__(256) void k_build(const int* __restrict__ tk_e, const float* __restrict__ tk_w,
                                               const int* __restrict__ offsets, int* __restrict__ cursors,
                                               int* __restrict__ tok_of, float* __restrict__ w_of,
                                               int* __restrict__ inv) {
  __shared__ int lcnt[NE], lbase[NE];
  int tid = threadIdx.x;
  int i = blockIdx.x * 256 + tid;
  if (tid < NE) lcnt[tid] = 0;
  __syncthreads();
  int e = tk_e[i];
  int local = atomicAdd(&lcnt[e], 1);
  __syncthreads();
  if (tid < NE) lbase[tid] = atomicAdd(&cursors[tid], lcnt[tid]);
  __syncthreads();
  int slot = offsets[e] + lbase[e] + local;
  tok_of[slot] = i >> 1;
  w_of[slot] = tk_w[i];
  inv[i] = slot;
}

// =====================================================================================
// Counted-vmcnt pipelined GEMMs (T3+T4+T5): BK=32, 4-deep LDS buffer ring, raw s_barrier,
// vmcnt(N) never drained to 0 mid-loop, setprio(1) around MFMA clusters.
// Granule swizzle (inherited from verified baseline): LDS slot s holds global k-chunk
// s ^ ((row>>1)&3); frag read: phys = (lane>>4) ^ ((row>>1)&3) -> conflict-free ds_read_b128.
// Residency proof: each tile = L loads/thread, stage tile T+3 during tile T. At the
// boundary before tile T+1, in-flight = tiles T+2,T+3 (2L loads) -> vmcnt(2L) guarantees
// tile T+1 landed; per-phase barriers make the guarantee collective across waves.
// =====================================================================================

#define LDS16(off) (*(const s16x8*)((const char*)smem + (off)))
#define VM8 asm volatile("s_waitcnt vmcnt(8)" ::: "memory")
#define VM6 asm volatile("s_waitcnt vmcnt(6)" ::: "memory")
#define VM4 asm volatile("s_waitcnt vmcnt(4)" ::: "memory")
#define VM3 asm volatile("s_waitcnt vmcnt(3)" ::: "memory")
#define VM0 asm volatile("s_waitcnt vmcnt(0)" ::: "memory")
#define NOVM do{}while(0)
#define NOSTG do{}while(0)
#define MFMA16 __builtin_amdgcn_mfma_f32_16x16x32_bf16

// ---------- GEMM1 macros: 256x256 tile, 8 waves (2x4), wave tile 128x64, acc[8][4] ----------
#define DS0_1(bb) do{ \
  bf0 = LDS16(offB0 + (bb)*32768); bf1 = LDS16(offB1 + (bb)*32768); \
  bf2 = LDS16(offB2 + (bb)*32768); bf3 = LDS16(offB3 + (bb)*32768); \
  af0 = LDS16(offA0 + (bb)*32768); af1 = LDS16(offA1 + (bb)*32768); \
  af2 = LDS16(offA2 + (bb)*32768); af3 = LDS16(offA3 + (bb)*32768); }while(0)
#define DS1_1(bb) do{ \
  af0 = LDS16(offA0 + (bb)*32768 + 4096); af1 = LDS16(offA1 + (bb)*32768 + 4096); \
  af2 = LDS16(offA2 + (bb)*32768 + 4096); af3 = LDS16(offA3 + (bb)*32768 + 4096); }while(0)
#define SA_1(bb) do{ \
  g2l16(gA0, (char*)smem + (bb)*32768 + wave*1024); \
  g2l16(gA1, (char*)smem + (bb)*32768 + 8192 + wave*1024); \
  gA0 += 32; gA1 += 32; }while(0)
#define SB_1(bb) do{ \
  g2l16(gB0, (char*)smem + (bb)*32768 + 16384 + wave*1024); \
  g2l16(gB1, (char*)smem + (bb)*32768 + 24576 + wave*1024); \
  gB0 += 32; gB1 += 32; }while(0)
#define MM16(H) do{ \
  __builtin_amdgcn_s_setprio(1); \
  acc[4*(H)+0][0] = MFMA16(af0, bf0, acc[4*(H)+0][0], 0, 0, 0); \
  acc[4*(H)+1][0] = MFMA16(af1, bf0, acc[4*(H)+1][0], 0, 0, 0); \
  acc[4*(H)+2][0] = MFMA16(af2, bf0, acc[4*(H)+2][0], 0, 0, 0); \
  acc[4*(H)+3][0] = MFMA16(af3, bf0, acc[4*(H)+3][0], 0, 0, 0); \
  acc[4*(H)+0][1] = MFMA16(af0, bf1, acc[4*(H)+0][1], 0, 0, 0); \
  acc[4*(H)+1][1] = MFMA16(af1, bf1, acc[4*(H)+1][1], 0, 0, 0); \
  acc[4*(H)+2][1] = MFMA16(af2, bf1, acc[4*(H)+2][1], 0, 0, 0); \
  acc[4*(H)+3][1] = MFMA16(af3, bf1, acc[4*(H)+3][1], 0, 0, 0); \
  acc[4*(H)+0][2] = MFMA16(af0, bf2, acc[4*(H)+0][2], 0, 0, 0); \
  acc[4*(H)+1][2] = MFMA16(af1, bf2, acc[4*(H)+1][2], 0, 0, 0); \
  acc[4*(H)+2][2] = MFMA16(af2, bf2, acc[4*(H)+2][2], 0, 0, 0); \
  acc[4*(H)+3][2] = MFMA16(af3, bf2, acc[4*(H)+3][2], 0, 0, 0); \
  acc[4*(H)+0][3] = MFMA16(af0, bf3, acc[4*(H)+0][3], 0, 0, 0); \
  acc[4*(H)+1][3] = MFMA16(af1, bf3, acc[4*(H)+1][3], 0, 0, 0); \
  acc[4*(H)+2][3] = MFMA16(af2, bf3, acc[4*(H)+2][3], 0, 0, 0); \
  acc[4*(H)+3][3] = MFMA16(af3, bf3, acc[4*(H)+3][3], 0, 0, 0); \
  __builtin_amdgcn_s_setprio(0); }while(0)
#define TILE1(bb, SA, SB, VMX) do{ \
  DS0_1(bb); SA; \
  __builtin_amdgcn_s_barrier(); \
  asm volatile("s_waitcnt lgkmcnt(0)" ::: "memory"); \
  MM16(0); \
  __builtin_amdgcn_s_barrier(); \
  DS1_1(bb); SB; \
  __builtin_amdgcn_s_barrier(); \
  asm volatile("s_waitcnt lgkmcnt(0)" ::: "memory"); \
  MM16(1); \
  VMX; \
  __builtin_amdgcn_s_barrier(); }while(0)

// ---------- GEMM1: h[slot][DFF] = relu(x[tok] @ W1[e] + b1[e]); 256x256 tile, K=512, NT=16 ----------
__global__ __launch_bounds__(512, 2) void k_gemm1(
    const uint16_t* __restrict__ xb, const uint16_t* __restrict__ w1t,
    const float* __restrict__ b1,
    const int* __restrict__ tok_of, const int* __restrict__ offsets,
    const int* __restrict__ trA, const int* __restrict__ tcntA, const int* __restrict__ tstartA,
    uint16_t* __restrict__ h) {
  __shared__ __align__(16) uint16_t smem[65536];   // 128KB: 4 bufs x (A 16KB + B 16KB)
  int id = blockIdx.x;
  int e = id & 7, j = id >> 3;                     // expert e -> XCD e
  int ti = j >> 3;
  if (ti >= tcntA[e]) return;
  int row0 = trA[tstartA[e] + ti], end = offsets[e + 1];
  int n0 = (j & 7) * 256;
  int tid = threadIdx.x, lane = tid & 63, wave = tid >> 6;
  int wm = wave >> 2, wn = wave & 3;
  int l15 = lane & 15, l4 = lane >> 4;

  int offA0, offA1, offA2, offA3, offB0, offB1, offB2, offB3;
  { int r;
    r = wm*128 + 0*16 + l15; offA0 = r*64 + ((l4 ^ ((r>>1)&3)) << 4);
    r = wm*128 + 1*16 + l15; offA1 = r*64 + ((l4 ^ ((r>>1)&3)) << 4);
    r = wm*128 + 2*16 + l15; offA2 = r*64 + ((l4 ^ ((r>>1)&3)) << 4);
    r = wm*128 + 3*16 + l15; offA3 = r*64 + ((l4 ^ ((r>>1)&3)) << 4);
    r = wn*64  + 0*16 + l15; offB0 = 16384 + r*64 + ((l4 ^ ((r>>1)&3)) << 4);
    r = wn*64  + 1*16 + l15; offB1 = 16384 + r*64 + ((l4 ^ ((r>>1)&3)) << 4);
    r = wn*64  + 2*16 + l15; offB2 = 16384 + r*64 + ((l4 ^ ((r>>1)&3)) << 4);
    r = wn*64  + 3*16 + l15; offB3 = 16384 + r*64 + ((l4 ^ ((r>>1)&3)) << 4);
  }
  const uint16_t *gA0, *gA1, *gB0, *gB1;
  { int P = tid, r = P >> 2, c = (P & 3) ^ ((r >> 1) & 3);
    int s = row0 + r; if (s >= end) s = end - 1;
    gA0 = xb + (size_t)tok_of[s] * DM + c * 8;
    gB0 = w1t + (size_t)e * DFF * DM + (size_t)(n0 + r) * DM + c * 8; }
  { int P = 512 + tid, r = P >> 2, c = (P & 3) ^ ((r >> 1) & 3);
    int s = row0 + r; if (s >= end) s = end - 1;
    gA1 = xb + (size_t)tok_of[s] * DM + c * 8;
    gB1 = w1t + (size_t)e * DFF * DM + (size_t)(n0 + r) * DM + c * 8; }

  f32x4 acc[8][4];
#pragma unroll
  for (int m = 0; m < 8; m++)
#pragma unroll
    for (int n = 0; n < 4; n++)
#pragma unroll
      for (int i = 0; i < 4; i++) acc[m][n][i] = 0.f;

  s16x8 af0, af1, af2, af3, bf0, bf1, bf2, bf3;

  // prologue: stage tiles 0,1,2; require tile 0 resident
  SA_1(0); SB_1(0); SA_1(1); SB_1(1); SA_1(2); SB_1(2);
  VM8;
  __builtin_amdgcn_s_barrier();

#pragma unroll 1
  for (int g = 0; g < 3; ++g) {                    // tiles 0..11 (NT=16)
    TILE1(0, SA_1(3), SB_1(3), VM8);
    TILE1(1, SA_1(0), SB_1(0), VM8);
    TILE1(2, SA_1(1), SB_1(1), VM8);
    TILE1(3, SA_1(2), SB_1(2), VM8);
  }
  TILE1(0, SA_1(3), SB_1(3), VM8);                 // tile 12 stages tile 15
  TILE1(1, NOSTG, NOSTG, VM4);                     // tile 13
  TILE1(2, NOSTG, NOSTG, VM0);                     // tile 14
  TILE1(3, NOSTG, NOSTG, NOVM);                    // tile 15

  // epilogue: bias+relu -> bf16, per-wave LDS repack (stride 144 = 16B-aligned, bank-spread)
  {
    float bv[4];
#pragma unroll
    for (int n = 0; n < 4; n++) bv[n] = b1[(size_t)e * DFF + n0 + wn * 64 + n * 16 + l15];
    char* wrg = (char*)smem + wave * 2304;
    int rr = lane >> 2, cb = lane & 3;
#pragma unroll
    for (int m = 0; m < 8; m++) {
#pragma unroll
      for (int n = 0; n < 4; n++)
#pragma unroll
        for (int i = 0; i < 4; i++) {
          float v = fmaxf(acc[m][n][i] + bv[n], 0.f);
          *(uint16_t*)(wrg + (l4 * 4 + i) * 144 + (n * 16 + l15) * 2) = f2b(v);
        }
      int gr = row0 + wm * 128 + m * 16 + rr;
      const char* src = wrg + rr * 144 + cb * 32;
      if (gr < end) {
        uint16_t* dst = h + (size_t)gr * DFF + n0 + wn * 64 + cb * 16;
        *(s16x8*)dst       = *(const s16x8*)src;
        *(s16x8*)(dst + 8) = *(const s16x8*)(src + 16);
      }
    }
  }
}

// ---------- GEMM2 macros: 128x256 tile, 8 waves (2x4), wave tile 64x64, acc[4][4] ----------
#define DS0_2(bb) do{ \
  bf0 = LDS16(offB0 + (bb)*24576); bf1 = LDS16(offB1 + (bb)*24576); \
  bf2 = LDS16(offB2 + (bb)*24576); bf3 = LDS16(offB3 + (bb)*24576); \
  af0 = LDS16(offA0 + (bb)*24576); af1 = LDS16(offA1 + (bb)*24576); }while(0)
#define DS1_2(bb) do{ \
  af0 = LDS16(offA2 + (bb)*24576); af1 = LDS16(offA3 + (bb)*24576); }while(0)
#define SA_2(bb) do{ \
  g2l16(gA0, (char*)smem + (bb)*24576 + wave*1024); \
  gA0 += 32; }while(0)
#define SB_2(bb) do{ \
  g2l16(gB0, (char*)smem + (bb)*24576 + 8192 + wave*1024); \
  g2l16(gB1, (char*)smem + (bb)*24576 + 16384 + wave*1024); \
  gB0 += 32; gB1 += 32; }while(0)
#define MM8(H) do{ \
  __builtin_amdgcn_s_setprio(1); \
  acc[2*(H)+0][0] = MFMA16(af0, bf0, acc[2*(H)+0][0], 0, 0, 0); \
  acc[2*(H)+1][0] = MFMA16(af1, bf0, acc[2*(H)+1][0], 0, 0, 0); \
  acc[2*(H)+0][1] = MFMA16(af0, bf1, acc[2*(H)+0][1], 0, 0, 0); \
  acc[2*(H)+1][1] = MFMA16(af1, bf1, acc[2*(H)+1][1], 0, 0, 0); \
  acc[2*(H)+0][2] = MFMA16(af0, bf2, acc[2*(H)+0][2], 0, 0, 0); \
  acc[2*(H)+1][2] = MFMA16(af1, bf2, acc[2*(H)+1][2], 0, 0, 0); \
  acc[2*(H)+0][3] = MFMA16(af0, bf3, acc[2*(H)+0][3], 0, 0, 0); \
  acc[2*(H)+1][3] = MFMA16(af1, bf3, acc[2*(H)+1][3], 0, 0, 0); \
  __builtin_amdgcn_s_setprio(0); }while(0)
#define TILE2(bb, SA, SB, VMX) do{ \
  DS0_2(bb); SA; \
  __builtin_amdgcn_s_barrier(); \
  asm volatile("s_waitcnt lgkmcnt(0)" ::: "memory"); \
  MM8(0); \
  __builtin_amdgcn_s_barrier(); \
  DS1_2(bb); SB; \
  __builtin_amdgcn_s_barrier(); \
  asm volatile("s_waitcnt lgkmcnt(0)" ::: "memory"); \
  MM8(1); \
  VMX; \
  __builtin_amdgcn_s_barrier(); }while(0)

// ---------- GEMM2: y[slot] = w_of[slot]*(h[slot] @ W2[e] + b2[e]); 128x256 tile, K=2048, NT=64 ----------
__global__ __launch_bounds__(512, 2) void k_gemm2(
    const uint16_t* __restrict__ h, const uint16_t* __restrict__ w2t,
    const float* __restrict__ b2, const float* __restrict__ w_of,
    const int* __restrict__ offsets,
    const int* __restrict__ trB, const int* __restrict__ tcntB, const int* __restrict__ tstartB,
    float* __restrict__ y32) {
  __shared__ __align__(16) uint16_t smem[49152];   // 96KB: 4 bufs x (A 8KB + B 16KB)
  int id = blockIdx.x;
  int e = id & 7, j = id >> 3;
  int ti = j >> 1;
  if (ti >= tcntB[e]) return;
  int row0 = trB[tstartB[e] + ti], end = offsets[e + 1];
  int n0 = (j & 1) * 256;
  int tid = threadIdx.x, lane = tid & 63, wave = tid >> 6;
  int wm = wave >> 2, wn = wave & 3;
  int l15 = lane & 15, l4 = lane >> 4;

  int offA0, offA1, offA2, offA3, offB0, offB1, offB2, offB3;
  { int r;
    r = wm*64 + 0*16 + l15; offA0 = r*64 + ((l4 ^ ((r>>1)&3)) << 4);
    r = wm*64 + 1*16 + l15; offA1 = r*64 + ((l4 ^ ((r>>1)&3)) << 4);
    r = wm*64 + 2*16 + l15; offA2 = r*64 + ((l4 ^ ((r>>1)&3)) << 4);
    r = wm*64 + 3*16 + l15; offA3 = r*64 + ((l4 ^ ((r>>1)&3)) << 4);
    r = wn*64 + 0*16 + l15; offB0 = 8192 + r*64 + ((l4 ^ ((r>>1)&3)) << 4);
    r = wn*64 + 1*16 + l15; offB1 = 8192 + r*64 + ((l4 ^ ((r>>1)&3)) << 4);
    r = wn*64 + 2*16 + l15; offB2 = 8192 + r*64 + ((l4 ^ ((r>>1)&3)) << 4);
    r = wn*64 + 3*16 + l15; offB3 = 8192 + r*64 + ((l4 ^ ((r>>1)&3)) << 4);
  }
  const uint16_t *gA0, *gB0, *gB1;
  { int P = tid, r = P >> 2, c = (P & 3) ^ ((r >> 1) & 3);
    int s = row0 + r; if (s >= end) s = end - 1;
    gA0 = h + (size_t)s * DFF + c * 8; }
  { int P = tid, r = P >> 2, c = (P & 3) ^ ((r >> 1) & 3);
    gB0 = w2t + (size_t)e * DM * DFF + (size_t)(n0 + r) * DFF + c * 8; }
  { int P = 512 + tid, r = P >> 2, c = (P & 3) ^ ((r >> 1) & 3);
    gB1 = w2t + (size_t)e * DM * DFF + (size_t)(n0 + r) * DFF + c * 8; }

  f32x4 acc[4][4];
#pragma unroll
  for (int m = 0; m < 4; m++)
#pragma unroll
    for (int n = 0; n < 4; n++)
#pragma unroll
      for (int i = 0; i < 4; i++) acc[m][n][i] = 0.f;

  s16x8 af0, af1, bf0, bf1, bf2, bf3;

  SA_2(0); SB_2(0); SA_2(1); SB_2(1); SA_2(2); SB_2(2);   // 9 loads/thread in flight
  VM6;
  __builtin_amdgcn_s_barrier();

#pragma unroll 1
  for (int g = 0; g < 15; ++g) {                   // tiles 0..59 (NT=64)
    TILE2(0, SA_2(3), SB_2(3), VM6);
    TILE2(1, SA_2(0), SB_2(0), VM6);
    TILE2(2, SA_2(1), SB_2(1), VM6);
    TILE2(3, SA_2(2), SB_2(2), VM6);
  }
  TILE2(0, SA_2(3), SB_2(3), VM6);                 // tile 60 stages tile 63
  TILE2(1, NOSTG, NOSTG, VM3);                     // tile 61
  TILE2(2, NOSTG, NOSTG, VM0);                     // tile 62
  TILE2(3, NOSTG, NOSTG, NOVM);                    // tile 63

  // epilogue: weighted bias add, direct fp32 stores (16-lane 64B runs)
  {
    float bv[4];
#pragma unroll
    for (int n = 0; n < 4; n++) bv[n] = b2[(size_t)e * DM + n0 + wn * 64 + n * 16 + l15];
#pragma unroll
    for (int m = 0; m < 4; m++)
#pragma unroll
      for (int i = 0; i < 4; i++) {
        int slot = row0 + wm * 64 + m * 16 + l4 * 4 + i;
        if (slot < end) {
          float wgt = w_of[slot];
          size_t base = (size_t)slot * DM + n0 + wn * 64 + l15;
          y32[base +  0] = wgt * (acc[m][0][i] + bv[0]);
          y32[base + 16] = wgt * (acc[m][1][i] + bv[1]);
          y32[base + 32] = wgt * (acc[m][2][i] + bv[2]);
          y32[base + 48] = wgt * (acc[m][3][i] + bv[3]);
        }
      }
  }
}

// ---------------- combine: out[tok] = y[slot0] + y[slot1] (weights pre-applied) ----------------
__global__ __launch_bounds__(256) void k_combine(const float* __restrict__ y32,
                                                 const int* __restrict__ inv,
                                                 float* __restrict__ out) {
  int tid = threadIdx.x;
  int tok = blockIdx.x * 2 + (tid >> 7);
  int c4 = (tid & 127) * 4;
  int s0 = inv[tok * 2], s1 = inv[tok * 2 + 1];
  const float4 a = *(const float4*)(y32 + (size_t)s0 * DM + c4);
  const float4 b = *(const float4*)(y32 + (size_t)s1 * DM + c4);
  *(float4*)(out + (size_t)tok * DM + c4) = make_float4(a.x + b.x, a.y + b.y, a.z + b.z, a.w + b.w);
}

extern "C" void kernel_launch(void* const* d_in, const int* in_sizes, int n_in,
                              void* d_out, int out_size, void* d_ws, size_t ws_size,
                              hipStream_t stream) {
  const float* x  = (const float*)d_in[0];
  const float* wg = (const float*)d_in[1];
  const float* w1 = (const float*)d_in[2];
  const float* b1 = (const float*)d_in[3];
  const float* w2 = (const float*)d_in[4];
  const float* b2 = (const float*)d_in[5];
  float* out = (float*)d_out;

  char* ws = (char*)d_ws;
  const size_t MB = 1024 * 1024;
  uint16_t* xb   = (uint16_t*)ws;                  // [0,16) MB
  uint16_t* w1t  = (uint16_t*)(ws + 16 * MB);      // [16,32) MB  [E][DFF][DM]
  uint16_t* w2t  = (uint16_t*)(ws + 32 * MB);      // [32,48) MB  [E][DM][DFF]
  uint16_t* hbuf = (uint16_t*)(ws + 48 * MB);      // [48,176) MB [NPAIR][DFF]
  int* ctrl = (int*)(ws + 176 * MB);               // [176,177) MB
  int*   counts  = ctrl;                 // 8
  int*   cursors = ctrl + 8;             // 8
  int*   offsets = ctrl + 16;            // 9
  int*   tcntA   = ctrl + 32;            // 8
  int*   tstartA = ctrl + 40;            // 8
  int*   trA     = ctrl + 48;            // 192 (ends 240)
  int*   tcntB   = ctrl + 240;           // 8
  int*   tstartB = ctrl + 248;           // 8
  int*   trB     = ctrl + 256;           // 384 (ends 640)
  int*   tk_e    = ctrl + 1024;
  float* tk_w    = (float*)(ctrl + 1024 + 32768);
  int*   tok_of  = ctrl + 1024 + 2 * 32768;
  float* w_of    = (float*)(ctrl + 1024 + 3 * 32768);
  int*   inv     = ctrl + 1024 + 4 * 32768;
  float* y32     = (float*)(ws + 177 * MB);        // [177,241) MB fp32 [NPAIR][DM]

  hipMemsetAsync(counts, 0, 16 * sizeof(int), stream);

  k_route<<<BTOK / 64, 256, 0, stream>>>(x, wg, counts, tk_e, tk_w, xb);
  k_tr<<<dim3(1024, 1, 16), dim3(32, 8), 0, stream>>>(w1, w2, w1t, w2t);
  k_setup<<<1, 64, 0, stream>>>(counts, offsets, trA, tcntA, tstartA, trB, tcntB, tstartB);
  k_build<<<NPAIR / 256, 256, 0, stream>>>(tk_e, tk_w, offsets, cursors, tok_of, w_of, inv);
  k_gemm1<<<NE * 8 * MAXTA, 512, 0, stream>>>(xb, w1t, b1, tok_of, offsets,
                                              trA, tcntA, tstartA, hbuf);
  k_gemm2<<<NE * 2 * MAXTB, 512, 0, stream>>>(hbuf, w2t, b2, w_of, offsets,
                                              trB, tcntB, tstartB, y32);
  k_combine<<<BTOK / 2, 256, 0, stream>>>(y32, inv, out);
}